// Round 3
// baseline (271.755 us; speedup 1.0000x reference)
//
#include <hip/hip_runtime.h>
#include <hip/hip_bf16.h>

// Problem: B=8, S=4096, D=768
//   y = tanh(x @ W); scores = y . v; w = softmax_S(scores); out = sum_s w * x
constexpr int Bb = 8;
constexpr int Ss = 4096;
constexpr int Dd = 768;
constexpr int Mm = Bb * Ss;      // 32768 rows

constexpr int BM = 64;           // rows per block
constexpr int KCH = 4;           // K staged in 4 chunks of 192

typedef __bf16 bf16x8 __attribute__((ext_vector_type(8)));
typedef __bf16 bf16x4 __attribute__((ext_vector_type(4)));
typedef float f32x4 __attribute__((ext_vector_type(4)));

__device__ __forceinline__ float fast_tanh(float x) {
    return 1.f - 2.f / (__expf(2.f * x) + 1.f);
}

// ---------------- Kernel 0: W[k][n] fp32 -> Wt[n][k] bf16 (LDS-tiled transpose)
__global__ __launch_bounds__(256) void convW(const float* __restrict__ W,
                                             __bf16* __restrict__ Wt) {
    __shared__ float tile[32][33];
    const int tx = threadIdx.x & 31;
    const int ty = threadIdx.x >> 5;
    const int kb = blockIdx.x * 32;
    const int nb = blockIdx.y * 32;
#pragma unroll
    for (int i = 0; i < 32; i += 8)
        tile[ty + i][tx] = W[(size_t)(kb + ty + i) * Dd + nb + tx];
    __syncthreads();
#pragma unroll
    for (int i = 0; i < 32; i += 8)
        Wt[(size_t)(nb + ty + i) * Dd + kb + tx] = (__bf16)tile[tx][ty + i];
}

// ---------------- Kernel 1: scores[m] = sum_n v[n]*tanh( (x@W)[m][n] )
// 512 blocks x 512 threads (8 waves). A staged in LDS in MFMA-fragment-major
// layout (each (kb,tm) fragment = contiguous 1KB -> conflict-free ds_read_b128),
// staged in 4 pipelined K-chunks so HBM latency hides under MFMA.
// Each wave owns 96 disjoint columns (6 x 16); B frags from L2-resident Wt.
__global__ __launch_bounds__(512, 2) void scores_gemm(
    const float* __restrict__ x, const __bf16* __restrict__ Wt,
    const float* __restrict__ v, float* __restrict__ scores) {
    __shared__ __bf16 As[24 * 4 * 64 * 8];   // (kb, tm, lane, j) = 98304 B
    __shared__ float sc_sh[8][BM];

    const int t = threadIdx.x;
    const int mb = blockIdx.x;
    const int lane = t & 63;
    const int w = t >> 6;                // wave 0..7
    const int quad = lane >> 4;
    const int lid = lane & 15;

    const float* xb = x + (size_t)mb * BM * Dd;

    // ---- staging helpers: one chunk = 64 rows x 192 k = 3072 float4, 6/thread
    float4 sreg[6];
    auto load_chunk = [&](int c) {
#pragma unroll
        for (int j = 0; j < 6; ++j) {
            const int idx = j * 512 + t;
            const int row = idx / 48;
            const int c4 = idx - row * 48;
            sreg[j] = *(const float4*)(xb + (size_t)row * Dd + c * 192 + c4 * 4);
        }
    };
    auto store_chunk = [&](int c) {
#pragma unroll
        for (int j = 0; j < 6; ++j) {
            const int idx = j * 512 + t;
            const int row = idx / 48;
            const int c4 = idx - row * 48;
            const int k0 = c * 192 + c4 * 4;
            const int kb = k0 >> 5;
            const int qd = (k0 >> 3) & 3;
            const int j0 = k0 & 7;
            const int tm = row >> 4;
            const int ld = row & 15;
            bf16x4 p;
            p[0] = (__bf16)sreg[j].x; p[1] = (__bf16)sreg[j].y;
            p[2] = (__bf16)sreg[j].z; p[3] = (__bf16)sreg[j].w;
            *(bf16x4*)(&As[(((kb * 4 + tm) * 64) + qd * 16 + ld) * 8 + j0]) = p;
        }
    };

    // ---- B pointers: wave w's 6 column tiles
    const __bf16* wp[6];
#pragma unroll
    for (int nt = 0; nt < 6; ++nt)
        wp[nt] = Wt + (size_t)(w * 96 + nt * 16 + lid) * Dd + quad * 8;

    f32x4 acc[4][6];
#pragma unroll
    for (int tm = 0; tm < 4; ++tm)
#pragma unroll
        for (int nt = 0; nt < 6; ++nt) acc[tm][nt] = (f32x4){0.f, 0.f, 0.f, 0.f};

    load_chunk(0);
    store_chunk(0);

    // B register prefetch (depth 1)
    bf16x8 bcur[6], bnxt[6];
#pragma unroll
    for (int nt = 0; nt < 6; ++nt) bcur[nt] = *(const bf16x8*)(wp[nt]);

    bf16x8 afc[4], afn[4];

    for (int c = 0; c < KCH; ++c) {
        __syncthreads();                     // chunk c LDS writes visible
        if (c < KCH - 1) load_chunk(c + 1);  // global loads cover under compute
        {
            const int kb = c * 6;
#pragma unroll
            for (int tm = 0; tm < 4; ++tm)
                afc[tm] = *(const bf16x8*)(&As[((kb * 4 + tm) * 64 + lane) * 8]);
        }
#pragma unroll
        for (int kk = 0; kk < 6; ++kk) {
            const int kb = c * 6 + kk;
            if (kb + 1 < 24) {
#pragma unroll
                for (int nt = 0; nt < 6; ++nt)
                    bnxt[nt] = *(const bf16x8*)(wp[nt] + (kb + 1) * 32);
            }
            if (kk < 5) {
#pragma unroll
                for (int tm = 0; tm < 4; ++tm)
                    afn[tm] = *(const bf16x8*)(&As[(((kb + 1) * 4 + tm) * 64 + lane) * 8]);
            }
#pragma unroll
            for (int tm = 0; tm < 4; ++tm)
#pragma unroll
                for (int nt = 0; nt < 6; ++nt)
                    acc[tm][nt] = __builtin_amdgcn_mfma_f32_16x16x32_bf16(afc[tm], bcur[nt], acc[tm][nt], 0, 0, 0);
#pragma unroll
            for (int tm = 0; tm < 4; ++tm) afc[tm] = afn[tm];
#pragma unroll
            for (int nt = 0; nt < 6; ++nt) bcur[nt] = bnxt[nt];
        }
        if (c < KCH - 1) store_chunk(c + 1);
    }

    // ---- epilogue: fold tanh * v, reduce across the 16 col-lanes, cross-wave sum
    float vv[6];
#pragma unroll
    for (int nt = 0; nt < 6; ++nt) vv[nt] = v[w * 96 + nt * 16 + lid];

#pragma unroll
    for (int tm = 0; tm < 4; ++tm)
#pragma unroll
        for (int r = 0; r < 4; ++r) {
            float s = 0.f;
#pragma unroll
            for (int nt = 0; nt < 6; ++nt) s += vv[nt] * fast_tanh(acc[tm][nt][r]);
            s += __shfl_xor(s, 1);
            s += __shfl_xor(s, 2);
            s += __shfl_xor(s, 4);
            s += __shfl_xor(s, 8);
            if (lid == 0) sc_sh[w][tm * 16 + quad * 4 + r] = s;
        }
    __syncthreads();
    if (t < BM) {
        float s = 0.f;
#pragma unroll
        for (int ww = 0; ww < 8; ++ww) s += sc_sh[ww][t];
        scores[mb * BM + t] = s;
    }
}

// ---------------- Kernel 2: softmax over S per batch row -> normalized weights
__global__ __launch_bounds__(256) void softmax_k(const float* __restrict__ scores,
                                                 float* __restrict__ weights) {
    const int b = blockIdx.x;
    const int t = threadIdx.x;
    const float* s = scores + (size_t)b * Ss;
    float* wgt = weights + (size_t)b * Ss;
    __shared__ float red[256];

    float mx = -1e30f;
    for (int i = t; i < Ss; i += 256) mx = fmaxf(mx, s[i]);
    red[t] = mx;
    __syncthreads();
    for (int o = 128; o > 0; o >>= 1) {
        if (t < o) red[t] = fmaxf(red[t], red[t + o]);
        __syncthreads();
    }
    mx = red[0];
    __syncthreads();
    float sum = 0.f;
    for (int i = t; i < Ss; i += 256) {
        const float e = __expf(s[i] - mx);
        wgt[i] = e;
        sum += e;
    }
    red[t] = sum;
    __syncthreads();
    for (int o = 128; o > 0; o >>= 1) {
        if (t < o) red[t] += red[t + o];
        __syncthreads();
    }
    const float inv = 1.f / red[0];
    for (int i = t; i < Ss; i += 256) wgt[i] *= inv;
}

// ---------------- Kernel 3: out[b][d] = sum_s w[b][s] * x[b][s][d]
// grid = (128 s-chunks, B), 192 threads; float4 per thread; 12 waves/CU.
__global__ __launch_bounds__(192) void pool_k(const float* __restrict__ x,
                                              const float* __restrict__ weights,
                                              float* __restrict__ out) {
    const int b = blockIdx.y;
    const int sc = blockIdx.x;           // 128 chunks x 32 rows
    const int t = threadIdx.x;           // 0..191
    const int s0 = sc * 32;
    float4 acc = make_float4(0.f, 0.f, 0.f, 0.f);
#pragma unroll 8
    for (int i = 0; i < 32; ++i) {
        const int s = s0 + i;
        const float ww = weights[(size_t)b * Ss + s];
        const float4 xv = *(const float4*)(x + ((size_t)b * Ss + s) * Dd + t * 4);
        acc.x += ww * xv.x;
        acc.y += ww * xv.y;
        acc.z += ww * xv.z;
        acc.w += ww * xv.w;
    }
    float* o = out + (size_t)b * Dd + t * 4;
    atomicAdd(o + 0, acc.x);
    atomicAdd(o + 1, acc.y);
    atomicAdd(o + 2, acc.z);
    atomicAdd(o + 3, acc.w);
}

extern "C" void kernel_launch(void* const* d_in, const int* in_sizes, int n_in,
                              void* d_out, int out_size, void* d_ws, size_t ws_size,
                              hipStream_t stream) {
    (void)in_sizes; (void)n_in; (void)ws_size;
    const float* x = (const float*)d_in[0];
    const float* v = (const float*)d_in[1];
    const float* W = (const float*)d_in[2];

    char* ws = (char*)d_ws;
    __bf16* Wt = (__bf16*)ws;                          // 1,179,648 B
    float* scores = (float*)(ws + 1179648);            //   131,072 B
    float* weights = (float*)(ws + 1179648 + 131072);  //   131,072 B

    hipMemsetAsync(d_out, 0, (size_t)out_size * sizeof(float), stream);

    convW<<<dim3(Dd / 32, Dd / 32), 256, 0, stream>>>(W, Wt);
    scores_gemm<<<dim3(Mm / BM), 512, 0, stream>>>(x, Wt, v, scores);
    softmax_k<<<dim3(Bb), 256, 0, stream>>>(scores, weights);
    pool_k<<<dim3(128, Bb), 192, 0, stream>>>(x, weights, (float*)d_out);
}